// Round 16
// baseline (66.405 us; speedup 1.0000x reference)
//
#include <hip/hip_runtime.h>
#include <math.h>

// DetectionLayer: x(32,255,76,76) f32 -> out(32,17328,85) f32
// R15 structure + FULL CACHE-BYPASS dump stores (sc0 sc1 nt).
// R13's nt-only stores still allocated in L3 (FETCH stayed 92MB): the 192MB
// output stream evicts half the 188MB input from the 256MB L3 every replay.
// sc0+sc1+nt = no-allocate at all cache levels (incl. MALL) on gfx950 ->
// input stays fully L3-resident across graph replays -> FETCH ~0.
//
// Block (512 thr) = (b, row i, j-half). jh=0: cols [0,40), jh=1: cols [40,76).
// Phase A : batched float4 loads (NQ=10|9 vec4/channel, 16B-aligned).
// Phase B : load-free transform -> output-layout LDS lds[j*255+c];
//           t==2|3 -> exp*anc partial, else sigm (final t>=4, partial t<2).
// Phase B2: corner fixup in LDS (JW*3 lanes, stride-85 access, conflict-free).
// Phase C : contiguous dwordx4 dump via inline asm "sc0 sc1 nt".
// LDS 40800B -> 4 blocks/CU x 8 waves = 32 waves/CU.
// XCD swizzle: logical (b,i,jh), jh fastest; 4864%8==0 -> bijective.

#define NCH    255
#define NATTR  85
#define HW     5776
#define GW     76
#define NBATCH 32
#define BLOCK  512
#define NWG    (NBATCH * GW * 2)   // 4864
#define CHUNK  (NWG / 8)           // 608

typedef float f32x4 __attribute__((ext_vector_type(4)));

__device__ __forceinline__ float sigm(float x) {
    return __builtin_amdgcn_rcpf(1.0f + __expf(-x));
}

__device__ __forceinline__ void store_bypass(f32x4* addr, f32x4 v) {
    asm volatile("global_store_dwordx4 %0, %1, off sc0 sc1 nt"
                 :: "v"(addr), "v"(v) : "memory");
}

template<int NQ>   // float4 units per channel: 10 (jh=0) or 9 (jh=1)
__device__ __forceinline__ void run_half(const float* __restrict__ src,
                                         float* __restrict__ dst,
                                         float* __restrict__ lds,
                                         int jg0, float fi) {
    constexpr int NU  = NCH * NQ;                  // 2550 / 2295 vec4 units
    constexpr int NIT = (NU + BLOCK - 1) / BLOCK;  // 5 / 5
    constexpr int JW  = 4 * NQ;                    // 40 / 36

    float4 xv[NIT];

    // ---- phase A: batched float4 loads ----
    #pragma unroll
    for (int k = 0; k < NIT; ++k) {
        int e = threadIdx.x + BLOCK * k;
        if (e < NU) {
            int c = e / NQ, q = e - c * NQ;
            xv[k] = *(const float4*)(src + (size_t)c * HW + 4 * q);
        }
    }

    // ---- phase B: load-free transform + output-layout LDS write ----
    #pragma unroll
    for (int k = 0; k < NIT; ++k) {
        int e = threadIdx.x + BLOCK * k;
        if (e < NU) {
            int c = e / NQ, q = e - c * NQ;
            int a = c / 85;              // exact (compiler magic-mul)
            int t = c - 85 * a;
            float4 v = xv[k];
            float r0, r1, r2, r3;
            if ((t | 1) == 3) {          // t==2 || t==3: half-extent partial
                float anc = ((t == 2)
                    ? ((a == 0) ? 10.f : (a == 1) ? 16.f : 33.f)
                    : ((a == 0) ? 13.f : (a == 1) ? 30.f : 23.f)) * (0.5f / 608.f);
                r0 = __expf(v.x) * anc; r1 = __expf(v.y) * anc;
                r2 = __expf(v.z) * anc; r3 = __expf(v.w) * anc;
            } else {                     // sigm: final t>=4, partial t<2
                r0 = sigm(v.x); r1 = sigm(v.y); r2 = sigm(v.z); r3 = sigm(v.w);
            }
            float* lp = &lds[(4 * q) * NCH + c];
            lp[0]       = r0;
            lp[NCH]     = r1;
            lp[2 * NCH] = r2;
            lp[3 * NCH] = r3;
        }
    }
    __syncthreads();

    // ---- phase B2: corner fixup in LDS (JW cols x 3 anchors) ----
    if (threadIdx.x < JW * 3) {
        int j = threadIdx.x / 3;
        int a = threadIdx.x - 3 * j;
        float* p = &lds[j * NCH + a * NATTR];
        float s0 = p[0], s1 = p[1], w2 = p[2], h2 = p[3];
        float ix = (s0 * 1.05f - 0.025f + (float)(jg0 + j)) * (1.0f / 76.0f);
        float iy = (s1 * 1.05f - 0.025f + fi) * (1.0f / 76.0f);
        p[0] = ix - w2; p[1] = iy - h2; p[2] = ix + w2; p[3] = iy + h2;
    }
    __syncthreads();

    // ---- phase C: contiguous dwordx4 dump, full cache bypass ----
    f32x4* __restrict__ dv = (f32x4*)dst;
    const f32x4* lv = (const f32x4*)lds;
    #pragma unroll
    for (int k = 0; k < NIT; ++k) {
        int e = threadIdx.x + BLOCK * k;
        if (e < NU) store_bypass(&dv[e], lv[e]);
    }
}

__global__ __launch_bounds__(BLOCK, 8) void det_kernel(const float* __restrict__ in,
                                                       float* __restrict__ out) {
    __shared__ float lds[NCH * 40];    // 40800 B -> 4 blocks/CU

    int hw = blockIdx.x;
    int L  = (hw & 7) * CHUNK + (hw >> 3);
    int jh = L & 1;
    int L2 = L >> 1;
    int i  = L2 % GW;
    int b  = L2 / GW;

    const float* __restrict__ src = in + (size_t)b * (NCH * HW) + (size_t)i * GW;
    float* __restrict__ dst = out + ((size_t)b * 17328 + (size_t)i * 228) * NATTR;
    const float fi = (float)i;

    if (jh == 0) {
        run_half<10>(src, dst, lds, 0, fi);
    } else {
        run_half<9>(src + 40, dst + 40 * NCH, lds, 40, fi);
    }
}

extern "C" void kernel_launch(void* const* d_in, const int* in_sizes, int n_in,
                              void* d_out, int out_size, void* d_ws, size_t ws_size,
                              hipStream_t stream) {
    const float* x = (const float*)d_in[0];
    float* out = (float*)d_out;
    det_kernel<<<NWG, BLOCK, 0, stream>>>(x, out);
}

// Round 17
// 65.530 us; speedup vs baseline: 1.0133x; 1.0133x over previous
//
#include <hip/hip_runtime.h>
#include <math.h>

// DetectionLayer: x(32,255,76,76) f32 -> out(32,17328,85) f32
// R15 structure, nt stores reverted to plain __builtin_nontemporal_store
// (R16's sc0/sc1 bits: -7us regression, FETCH unchanged -> reverted), and
// TWO TILES PER BLOCK with all loads issued upfront:
//   Block (512 thr) = (b, row i). Issue all 10 float4 loads (both j-halves,
//   40 data VGPRs) behind a scheduling fence, then per half:
//   transform -> LDS (output layout) -> sync -> corner fixup -> sync ->
//   NT float4 dump -> sync -> next half (registers loaded ~2us earlier).
// Halves block count (4864->2432): half the cold-start load latencies and
// block-churn; half-1 latency rides under half-0 compute+dump.
// LDS 40800B (reused per half) -> 4 blocks/CU x 8 waves = 32 waves/CU.
// XCD swizzle: logical (b,i) chunked; 2432%8==0 -> bijective.

#define NCH    255
#define NATTR  85
#define HW     5776
#define GW     76
#define NBATCH 32
#define BLOCK  512
#define NWG    (NBATCH * GW)       // 2432
#define CHUNK  (NWG / 8)           // 304

typedef float f32x4 __attribute__((ext_vector_type(4)));

__device__ __forceinline__ float sigm(float x) {
    return __builtin_amdgcn_rcpf(1.0f + __expf(-x));
}

template<int NQ>   // float4 units per channel this half: 10 | 9
__device__ __forceinline__ void load_half(const float* __restrict__ src,
                                          float4* __restrict__ xv) {
    constexpr int NU = NCH * NQ;
    #pragma unroll
    for (int k = 0; k < 5; ++k) {
        int e = threadIdx.x + BLOCK * k;
        if (e < NU) {
            int c = e / NQ, q = e - c * NQ;
            xv[k] = *(const float4*)(src + (size_t)c * HW + 4 * q);
        }
    }
}

template<int NQ>
__device__ __forceinline__ void process_half(const float4* __restrict__ xv,
                                             float* __restrict__ dst,
                                             float* __restrict__ lds,
                                             int jg0, float fi) {
    constexpr int NU = NCH * NQ;
    constexpr int JW = 4 * NQ;

    // ---- transform (load-free) + output-layout LDS write ----
    #pragma unroll
    for (int k = 0; k < 5; ++k) {
        int e = threadIdx.x + BLOCK * k;
        if (e < NU) {
            int c = e / NQ, q = e - c * NQ;
            int a = c / 85;              // exact (compiler magic-mul)
            int t = c - 85 * a;
            float4 v = xv[k];
            float r0, r1, r2, r3;
            if ((t | 1) == 3) {          // t==2 || t==3: half-extent partial
                float anc = ((t == 2)
                    ? ((a == 0) ? 10.f : (a == 1) ? 16.f : 33.f)
                    : ((a == 0) ? 13.f : (a == 1) ? 30.f : 23.f)) * (0.5f / 608.f);
                r0 = __expf(v.x) * anc; r1 = __expf(v.y) * anc;
                r2 = __expf(v.z) * anc; r3 = __expf(v.w) * anc;
            } else {                     // sigm: final t>=4, partial t<2
                r0 = sigm(v.x); r1 = sigm(v.y); r2 = sigm(v.z); r3 = sigm(v.w);
            }
            float* lp = &lds[(4 * q) * NCH + c];
            lp[0]       = r0;
            lp[NCH]     = r1;
            lp[2 * NCH] = r2;
            lp[3 * NCH] = r3;
        }
    }
    __syncthreads();

    // ---- corner fixup in LDS (JW cols x 3 anchors) ----
    if (threadIdx.x < JW * 3) {
        int j = threadIdx.x / 3;
        int a = threadIdx.x - 3 * j;
        float* p = &lds[j * NCH + a * NATTR];
        float s0 = p[0], s1 = p[1], w2 = p[2], h2 = p[3];
        float ix = (s0 * 1.05f - 0.025f + (float)(jg0 + j)) * (1.0f / 76.0f);
        float iy = (s1 * 1.05f - 0.025f + fi) * (1.0f / 76.0f);
        p[0] = ix - w2; p[1] = iy - h2; p[2] = ix + w2; p[3] = iy + h2;
    }
    __syncthreads();

    // ---- contiguous float4 NON-TEMPORAL dump ----
    f32x4* __restrict__ dv = (f32x4*)dst;
    const f32x4* lv = (const f32x4*)lds;
    #pragma unroll
    for (int k = 0; k < 5; ++k) {
        int e = threadIdx.x + BLOCK * k;
        if (e < NU) __builtin_nontemporal_store(lv[e], &dv[e]);
    }
}

__global__ __launch_bounds__(BLOCK, 8) void det_kernel(const float* __restrict__ in,
                                                       float* __restrict__ out) {
    __shared__ float lds[NCH * 40];    // 40800 B -> 4 blocks/CU

    int hw = blockIdx.x;
    int L  = (hw & 7) * CHUNK + (hw >> 3);
    int i  = L % GW;
    int b  = L / GW;

    const float* __restrict__ src = in + (size_t)b * (NCH * HW) + (size_t)i * GW;
    float* __restrict__ dst = out + ((size_t)b * 17328 + (size_t)i * 228) * NATTR;
    const float fi = (float)i;

    float4 x0[5], x1[5];
    load_half<10>(src, x0);            // cols [0,40)
    load_half<9>(src + 40, x1);        // cols [40,76) -- issued upfront
    asm volatile("" ::: "memory");     // pin loads before any use

    process_half<10>(x0, dst, lds, 0, fi);
    __syncthreads();                   // dump0 ds_reads done before reuse
    process_half<9>(x1, dst + 40 * NCH, lds, 40, fi);
}

extern "C" void kernel_launch(void* const* d_in, const int* in_sizes, int n_in,
                              void* d_out, int out_size, void* d_ws, size_t ws_size,
                              hipStream_t stream) {
    const float* x = (const float*)d_in[0];
    float* out = (float*)d_out;
    det_kernel<<<NWG, BLOCK, 0, stream>>>(x, out);
}

// Round 18
// 59.495 us; speedup vs baseline: 1.1161x; 1.1014x over previous
//
#include <hip/hip_runtime.h>
#include <math.h>

// DetectionLayer: x(32,255,76,76) f32 -> out(32,17328,85) f32
// FINAL (revert to measured-best R14 structure, 59.3us wall).
// Session summary of what matters on this op (MI355X):
//  - output-layout LDS staging + contiguous NT float4 dumps (R13: -24%)
//  - full-row 304B input read geometry, batched float4 loads
//  - 40800B LDS -> 4 blocks/CU x 8 waves; single cheap barrier
//  - bijective XCD-chunked bid swizzle
// Nulls/regressions: sc0/sc1 cache-bypass (-12%), 2-tile blocks (-10%),
// load fences (null), in-LDS corner fixup (null), channel-split (-12%).
// Plateau: 280MB HBM @ 4.7TB/s, WRITE=output size, FETCH=input w/ 50% L3
// absorption -> practical mixed-stream roofline.

#define NCH    255
#define NATTR  85
#define HW     5776
#define GW     76
#define NBATCH 32
#define BLOCK  512
#define NWG    (NBATCH * GW * 2)   // 4864
#define CHUNK  (NWG / 8)           // 608

typedef float f32x4 __attribute__((ext_vector_type(4)));

__device__ __forceinline__ float sigm(float x) {
    return __builtin_amdgcn_rcpf(1.0f + __expf(-x));
}

template<int NQ>   // float4 units per channel: 10 (jh=0) or 9 (jh=1)
__device__ __forceinline__ void run_half(const float* __restrict__ src,
                                         float* __restrict__ dst,
                                         float* __restrict__ lds,
                                         int jg0, float fi) {
    constexpr int NU  = NCH * NQ;                  // 2550 / 2295 vec4 units
    constexpr int NIT = (NU + BLOCK - 1) / BLOCK;  // 5 / 5

    float4 xv[NIT];

    // ---- phase A: batched float4 loads ----
    #pragma unroll
    for (int k = 0; k < NIT; ++k) {
        int e = threadIdx.x + BLOCK * k;
        if (e < NU) {
            int c = e / NQ, q = e - c * NQ;
            xv[k] = *(const float4*)(src + (size_t)c * HW + 4 * q);
        }
    }
    asm volatile("" ::: "memory");

    // ---- phase B: transform + output-layout LDS write ----
    #pragma unroll
    for (int k = 0; k < NIT; ++k) {
        int e = threadIdx.x + BLOCK * k;
        if (e < NU) {
            int c = e / NQ, q = e - c * NQ;
            int a = c / 85;              // exact (compiler magic-mul)
            int t = c - 85 * a;
            float4 v = xv[k];
            float r0, r1, r2, r3;
            if (t >= 4) {
                r0 = sigm(v.x); r1 = sigm(v.y); r2 = sigm(v.z); r3 = sigm(v.w);
            } else {
                int cp = (t < 2) ? c + 2 : c - 2;      // partner (cache-warm)
                float4 pv = *(const float4*)(src + (size_t)cp * HW + 4 * q);
                float ancw = (a == 0) ? 10.f : (a == 1) ? 16.f : 33.f;
                float anch = (a == 0) ? 13.f : (a == 1) ? 30.f : 23.f;
                float anc  = ((t & 1) ? anch : ancw) * (0.5f / 608.f);
                float vv[4] = {v.x, v.y, v.z, v.w};
                float pp[4] = {pv.x, pv.y, pv.z, pv.w};
                float rr[4];
                #pragma unroll
                for (int m = 0; m < 4; ++m) {
                    float coord = (t & 1) ? fi : (float)(jg0 + 4 * q + m);
                    float sin_ = (t < 2) ? vv[m] : pp[m];   // sigmoid input
                    float ein_ = (t < 2) ? pp[m] : vv[m];   // exp input
                    float ixy = (sigm(sin_) * 1.05f - 0.025f + coord) * (1.0f / 76.0f);
                    float wh2 = __expf(ein_) * anc;
                    rr[m] = (t < 2) ? (ixy - wh2) : (ixy + wh2);
                }
                r0 = rr[0]; r1 = rr[1]; r2 = rr[2]; r3 = rr[3];
            }
            float* lp = &lds[(4 * q) * NCH + c];
            lp[0]       = r0;
            lp[NCH]     = r1;
            lp[2 * NCH] = r2;
            lp[3 * NCH] = r3;
        }
    }
    __syncthreads();

    // ---- phase C: contiguous float4 NON-TEMPORAL dump ----
    f32x4* __restrict__ dv = (f32x4*)dst;
    const f32x4* lv = (const f32x4*)lds;
    #pragma unroll
    for (int k = 0; k < NIT; ++k) {
        int e = threadIdx.x + BLOCK * k;
        if (e < NU) __builtin_nontemporal_store(lv[e], &dv[e]);
    }
}

__global__ __launch_bounds__(BLOCK, 8) void det_kernel(const float* __restrict__ in,
                                                       float* __restrict__ out) {
    __shared__ float lds[NCH * 40];    // 40800 B -> 4 blocks/CU

    int hw = blockIdx.x;
    int L  = (hw & 7) * CHUNK + (hw >> 3);
    int jh = L & 1;
    int L2 = L >> 1;
    int i  = L2 % GW;
    int b  = L2 / GW;

    const float* __restrict__ src = in + (size_t)b * (NCH * HW) + (size_t)i * GW;
    float* __restrict__ dst = out + ((size_t)b * 17328 + (size_t)i * 228) * NATTR;
    const float fi = (float)i;

    if (jh == 0) {
        run_half<10>(src, dst, lds, 0, fi);
    } else {
        run_half<9>(src + 40, dst + 40 * NCH, lds, 40, fi);
    }
}

extern "C" void kernel_launch(void* const* d_in, const int* in_sizes, int n_in,
                              void* d_out, int out_size, void* d_ws, size_t ws_size,
                              hipStream_t stream) {
    const float* x = (const float*)d_in[0];
    float* out = (float*)d_out;
    det_kernel<<<NWG, BLOCK, 0, stream>>>(x, out);
}